// Round 5
// baseline (133.926 us; speedup 1.0000x reference)
//
#include <hip/hip_runtime.h>

#define BB 4096
#define FF 39
#define DD 128
#define FIELD_DIM 10000
#define NITEMS (BB * FF)          // 159744
#define ROWS_WS_BYTES ((size_t)8 * NITEMS * 16)   // 20,447,232

// ============================ Pass 1 =====================================
// One thread per item, f-major + XCD-chunked (idx tables L2-resident).
// For each d-slice h in [0,8): write a 16 B record
//   {r00, r10, r20, r11[h>>2], r21[h>>2], r12[h>>1], r22[h>>1], 0} as u16.
// (all row counts <= 19968 < 65536, so u16 is lossless)
__global__ __launch_bounds__(256) void pass1_resolve(
    const int* __restrict__ x,
    const int* __restrict__ i00, const int* __restrict__ i10,
    const int* __restrict__ i11, const int* __restrict__ i12,
    const int* __restrict__ i20, const int* __restrict__ i21,
    const int* __restrict__ i22,
    uint4* __restrict__ rows_ws)
{
    const int nwg = gridDim.x;              // 624, %8==0
    const int cpx = nwg >> 3;
    const int blk = blockIdx.x;
    const int wg  = (blk & 7) * cpx + (blk >> 3);
    const int i   = wg * 256 + (int)threadIdx.x;   // f-major item id
    const int f   = i >> 12;
    const int b   = i & (BB - 1);
    const int xg  = x[b * FF + f] + f * FIELD_DIM;

    const unsigned r00 = (unsigned)i00[xg];
    const unsigned r10 = (unsigned)i10[xg];
    const unsigned r20 = (unsigned)i20[xg];
    const int2 v11 = *reinterpret_cast<const int2*>(i11 + (size_t)xg * 2);
    const int2 v21 = *reinterpret_cast<const int2*>(i21 + (size_t)xg * 2);
    const int4 v12 = *reinterpret_cast<const int4*>(i12 + (size_t)xg * 4);
    const int4 v22 = *reinterpret_cast<const int4*>(i22 + (size_t)xg * 4);

    const unsigned r11_0 = (unsigned)v11.x, r11_1 = (unsigned)v11.y;
    const unsigned r21_0 = (unsigned)v21.x, r21_1 = (unsigned)v21.y;
    const unsigned r12_0 = (unsigned)v12.x, r12_1 = (unsigned)v12.y;
    const unsigned r12_2 = (unsigned)v12.z, r12_3 = (unsigned)v12.w;
    const unsigned r22_0 = (unsigned)v22.x, r22_1 = (unsigned)v22.y;
    const unsigned r22_2 = (unsigned)v22.z, r22_3 = (unsigned)v22.w;

    const unsigned w0 = r00 | (r10 << 16);

#define EMIT(h, a, b4)                                                        \
    do {                                                                      \
        uint4 rec;                                                            \
        rec.x = w0;                                                           \
        rec.y = r20 | (r11_##a << 16);                                        \
        rec.z = r21_##a | (r12_##b4 << 16);                                   \
        rec.w = r22_##b4;                                                     \
        rows_ws[(size_t)(h) * NITEMS + i] = rec;                              \
    } while (0)

    EMIT(0, 0, 0); EMIT(1, 0, 0); EMIT(2, 0, 1); EMIT(3, 0, 1);
    EMIT(4, 1, 2); EMIT(5, 1, 2); EMIT(6, 1, 3); EMIT(7, 1, 3);
#undef EMIT
}

// ============================ Pass 2 =====================================
// d-split x8: XCD h owns d in [h*16, h*16+16) for ALL items. Per-book line
// pool per XCD = rows*64B (0.6-1.3 MB) -> fits 4 MB L2, reuse ~8x captured.
// Block: 256 threads = 64 items x 4 lanes (float4 each).
__global__ __launch_bounds__(256) void pass2_gather(
    const float* __restrict__ arch_prob,
    const float* __restrict__ cb00, const float* __restrict__ cb10,
    const float* __restrict__ cb11, const float* __restrict__ cb12,
    const float* __restrict__ cb20, const float* __restrict__ cb21,
    const float* __restrict__ cb22,
    const uint4* __restrict__ rows_ws,
    float* __restrict__ out)
{
    const int blk  = blockIdx.x;
    const int h    = blk & 7;               // d-slice == XCD (round-robin)
    const int seq  = blk >> 3;              // sequential item chunk per XCD
    const int t    = (int)threadIdx.x;
    const int item = seq * 64 + (t >> 2);
    const int sub  = t & 3;
    const int d0   = h * 16 + sub * 4;
    const int f    = item >> 12;
    const int b    = item & (BB - 1);

    const uint4 rw = rows_ws[(size_t)h * NITEMS + item];
    const int r00 = (int)(rw.x & 0xffffu), r10 = (int)(rw.x >> 16);
    const int r20 = (int)(rw.y & 0xffffu), r11 = (int)(rw.y >> 16);
    const int r21 = (int)(rw.z & 0xffffu), r12 = (int)(rw.z >> 16);
    const int r22 = (int)(rw.w & 0xffffu);

    const float* ap = arch_prob + f * 9;

    float4 acc = make_float4(0.f, 0.f, 0.f, 0.f);

#define GATHER_FMA(cb, r, col)                                                \
    do {                                                                      \
        float4 v = *reinterpret_cast<const float4*>((cb) + (size_t)(r) * DD + d0); \
        float s = ap[col];                                                    \
        acc.x += s * v.x; acc.y += s * v.y;                                   \
        acc.z += s * v.z; acc.w += s * v.w;                                   \
    } while (0)

    // Reference pair order -> identical fp32 accumulation order.
    GATHER_FMA(cb00, r00, 0);
    GATHER_FMA(cb10, r10, 3);
    GATHER_FMA(cb11, r11, 4);
    GATHER_FMA(cb12, r12, 5);
    GATHER_FMA(cb20, r20, 6);
    GATHER_FMA(cb21, r21, 7);
    GATHER_FMA(cb22, r22, 8);
#undef GATHER_FMA

    float* dst = out + ((size_t)b * FF + f) * DD + d0;
    __builtin_nontemporal_store(acc.x, dst + 0);
    __builtin_nontemporal_store(acc.y, dst + 1);
    __builtin_nontemporal_store(acc.z, dst + 2);
    __builtin_nontemporal_store(acc.w, dst + 3);
}

// ===================== Fallback (R3 single-pass) =========================
__global__ __launch_bounds__(256) void mixq_embed(
    const int* __restrict__ x,
    const float* __restrict__ arch_prob,
    const float* __restrict__ cb00, const int* __restrict__ i00,
    const float* __restrict__ cb10, const int* __restrict__ i10,
    const float* __restrict__ cb11, const int* __restrict__ i11,
    const float* __restrict__ cb12, const int* __restrict__ i12,
    const float* __restrict__ cb20, const int* __restrict__ i20,
    const float* __restrict__ cb21, const int* __restrict__ i21,
    const float* __restrict__ cb22, const int* __restrict__ i22,
    float* __restrict__ out)
{
    const int nwg  = gridDim.x;
    const int perx = nwg >> 3;
    const int blk  = blockIdx.x;
    const int xcd  = blk & 7;
    const int hh   = xcd >> 2;
    const int wh   = (xcd & 3) * perx + (blk >> 3);

    const int t   = (int)threadIdx.x;
    const int sub = (t >> 4) & 1;
    const int li  = t & 15;
    const int ii  = wh * 16 + ((t >> 5) << 1) + sub;
    const int f   = ii >> 12;
    const int bb  = ii & (BB - 1);
    const int d0  = (hh << 6) + (li << 2);

    const int xg = x[bb * FF + f] + f * FIELD_DIM;
    const float* ap = arch_prob + f * 9;
    const int k4 = (hh << 1) + (li >> 3);

    int r00 = i00[xg];
    int r10 = i10[xg];
    int r11 = i11[(size_t)xg * 2 + hh];
    int r12 = i12[(size_t)xg * 4 + k4];
    int r20 = i20[xg];
    int r21 = i21[(size_t)xg * 2 + hh];
    int r22 = i22[(size_t)xg * 4 + k4];

    float4 acc = make_float4(0.f, 0.f, 0.f, 0.f);

#define GATHER_FMA(cb, r, col)                                                \
    do {                                                                      \
        float4 v = *reinterpret_cast<const float4*>((cb) + (size_t)(r) * DD + d0); \
        float s = ap[col];                                                    \
        acc.x += s * v.x; acc.y += s * v.y;                                   \
        acc.z += s * v.z; acc.w += s * v.w;                                   \
    } while (0)

    GATHER_FMA(cb00, r00, 0);
    GATHER_FMA(cb10, r10, 3);
    GATHER_FMA(cb11, r11, 4);
    GATHER_FMA(cb12, r12, 5);
    GATHER_FMA(cb20, r20, 6);
    GATHER_FMA(cb21, r21, 7);
    GATHER_FMA(cb22, r22, 8);
#undef GATHER_FMA

    float* dst = out + ((size_t)bb * FF + f) * DD + d0;
    __builtin_nontemporal_store(acc.x, dst + 0);
    __builtin_nontemporal_store(acc.y, dst + 1);
    __builtin_nontemporal_store(acc.z, dst + 2);
    __builtin_nontemporal_store(acc.w, dst + 3);
}

extern "C" void kernel_launch(void* const* d_in, const int* in_sizes, int n_in,
                              void* d_out, int out_size, void* d_ws, size_t ws_size,
                              hipStream_t stream) {
    const int*   x  = (const int*)d_in[0];
    const float* ap = (const float*)d_in[1];
    const float* cb00 = (const float*)d_in[2];
    const int*   i00  = (const int*)d_in[3];
    const float* cb10 = (const float*)d_in[4];
    const int*   i10  = (const int*)d_in[5];
    const float* cb11 = (const float*)d_in[6];
    const int*   i11  = (const int*)d_in[7];
    const float* cb12 = (const float*)d_in[8];
    const int*   i12  = (const int*)d_in[9];
    const float* cb20 = (const float*)d_in[10];
    const int*   i20  = (const int*)d_in[11];
    const float* cb21 = (const float*)d_in[12];
    const int*   i21  = (const int*)d_in[13];
    const float* cb22 = (const float*)d_in[14];
    const int*   i22  = (const int*)d_in[15];
    float* out = (float*)d_out;

    if (ws_size >= ROWS_WS_BYTES) {
        uint4* rows_ws = (uint4*)d_ws;
        pass1_resolve<<<NITEMS / 256, 256, 0, stream>>>(
            x, i00, i10, i11, i12, i20, i21, i22, rows_ws);
        pass2_gather<<<(NITEMS / 64) * 8, 256, 0, stream>>>(
            ap, cb00, cb10, cb11, cb12, cb20, cb21, cb22, rows_ws, out);
    } else {
        const long long total_threads = (long long)BB * FF * 32;
        const int blocks = (int)((total_threads + 255) / 256);
        mixq_embed<<<blocks, 256, 0, stream>>>(
            x, ap, cb00, i00, cb10, i10, cb11, i11, cb12, i12,
            cb20, i20, cb21, i21, cb22, i22, out);
    }
}

// Round 6
// 80.159 us; speedup vs baseline: 1.6708x; 1.6708x over previous
//
#include <hip/hip_runtime.h>

#define BB 4096
#define FF 39
#define DD 128
#define FIELD_DIM 10000
#define NITEMS (BB * FF)          // 159744
#define ROWS_WS_BYTES ((size_t)4 * NITEMS * 16)   // 10,223,616

// ============================ Pass 1 =====================================
// One thread per item, f-major + XCD-chunked (idx tables L2-resident).
// For each d-QUARTER q in [0,4): 16 B record
//   {r00, r10, r20, r11[q>>1], r21[q>>1], r12[q], r22[q]} as u16
// (row counts <= 19968 < 65536 -> u16 lossless).
__global__ __launch_bounds__(256) void pass1_resolve(
    const int* __restrict__ x,
    const int* __restrict__ i00, const int* __restrict__ i10,
    const int* __restrict__ i11, const int* __restrict__ i12,
    const int* __restrict__ i20, const int* __restrict__ i21,
    const int* __restrict__ i22,
    uint4* __restrict__ rows_ws)
{
    const int nwg = gridDim.x;              // 624, %8==0
    const int cpx = nwg >> 3;
    const int blk = blockIdx.x;
    const int wg  = (blk & 7) * cpx + (blk >> 3);
    const int i   = wg * 256 + (int)threadIdx.x;   // f-major item id
    const int f   = i >> 12;
    const int b   = i & (BB - 1);
    const int xg  = x[b * FF + f] + f * FIELD_DIM;

    const unsigned r00 = (unsigned)i00[xg];
    const unsigned r10 = (unsigned)i10[xg];
    const unsigned r20 = (unsigned)i20[xg];
    const int2 v11 = *reinterpret_cast<const int2*>(i11 + (size_t)xg * 2);
    const int2 v21 = *reinterpret_cast<const int2*>(i21 + (size_t)xg * 2);
    const int4 v12 = *reinterpret_cast<const int4*>(i12 + (size_t)xg * 4);
    const int4 v22 = *reinterpret_cast<const int4*>(i22 + (size_t)xg * 4);

    const unsigned w0 = r00 | (r10 << 16);
    const unsigned r11k[2] = { (unsigned)v11.x, (unsigned)v11.y };
    const unsigned r21k[2] = { (unsigned)v21.x, (unsigned)v21.y };
    const unsigned r12k[4] = { (unsigned)v12.x, (unsigned)v12.y,
                               (unsigned)v12.z, (unsigned)v12.w };
    const unsigned r22k[4] = { (unsigned)v22.x, (unsigned)v22.y,
                               (unsigned)v22.z, (unsigned)v22.w };

#pragma unroll
    for (int q = 0; q < 4; ++q) {
        uint4 rec;
        rec.x = w0;
        rec.y = r20 | (r11k[q >> 1] << 16);
        rec.z = r21k[q >> 1] | (r12k[q] << 16);
        rec.w = r22k[q];
        rows_ws[(size_t)q * NITEMS + i] = rec;
    }
}

// ============================ Pass 2 =====================================
// d-QUARTER split: XCD pair {2q,2q+1} owns d in [q*32, q*32+32) — gathers are
// 128 B = one full L2 line (no straddle waste). Items split across the pair,
// so per-XCD per-book slice pool is 1.25-2.5 MB. Block: 256 thr = 32 items
// x 8 lanes (float4 each).
__global__ __launch_bounds__(256) void pass2_gather(
    const float* __restrict__ arch_prob,
    const float* __restrict__ cb00, const float* __restrict__ cb10,
    const float* __restrict__ cb11, const float* __restrict__ cb12,
    const float* __restrict__ cb20, const float* __restrict__ cb21,
    const float* __restrict__ cb22,
    const uint4* __restrict__ rows_ws,
    float* __restrict__ out)
{
    const int blk = blockIdx.x;               // 19968 blocks
    const int xcd = blk & 7;
    const int q   = xcd >> 1;                 // d-quarter owned by this XCD pair
    const int ph  = xcd & 1;                  // item half within the pair
    const int seq = blk >> 3;                 // [0, 2496)

    const int t   = (int)threadIdx.x;
    const int li  = t & 7;                    // lane within item
    const int ii  = ph * (NITEMS / 2) + seq * 32 + (t >> 3);  // f-major item
    const int f   = ii >> 12;
    const int b   = ii & (BB - 1);
    const int d0  = q * 32 + li * 4;

    const uint4 rw = rows_ws[(size_t)q * NITEMS + ii];
    const int r00 = (int)(rw.x & 0xffffu), r10 = (int)(rw.x >> 16);
    const int r20 = (int)(rw.y & 0xffffu), r11 = (int)(rw.y >> 16);
    const int r21 = (int)(rw.z & 0xffffu), r12 = (int)(rw.z >> 16);
    const int r22 = (int)(rw.w & 0xffffu);

    const float* ap = arch_prob + f * 9;

    float4 acc = make_float4(0.f, 0.f, 0.f, 0.f);

#define GATHER_FMA(cb, r, col)                                                \
    do {                                                                      \
        float4 v = *reinterpret_cast<const float4*>((cb) + (size_t)(r) * DD + d0); \
        float s = ap[col];                                                    \
        acc.x += s * v.x; acc.y += s * v.y;                                   \
        acc.z += s * v.z; acc.w += s * v.w;                                   \
    } while (0)

    // Reference pair order -> identical fp32 accumulation order.
    GATHER_FMA(cb00, r00, 0);
    GATHER_FMA(cb10, r10, 3);
    GATHER_FMA(cb11, r11, 4);
    GATHER_FMA(cb12, r12, 5);
    GATHER_FMA(cb20, r20, 6);
    GATHER_FMA(cb21, r21, 7);
    GATHER_FMA(cb22, r22, 8);
#undef GATHER_FMA

    float* dst = out + ((size_t)b * FF + f) * DD + d0;
    __builtin_nontemporal_store(acc.x, dst + 0);
    __builtin_nontemporal_store(acc.y, dst + 1);
    __builtin_nontemporal_store(acc.z, dst + 2);
    __builtin_nontemporal_store(acc.w, dst + 3);
}

// ===================== Fallback (R3 single-pass) =========================
__global__ __launch_bounds__(256) void mixq_embed(
    const int* __restrict__ x,
    const float* __restrict__ arch_prob,
    const float* __restrict__ cb00, const int* __restrict__ i00,
    const float* __restrict__ cb10, const int* __restrict__ i10,
    const float* __restrict__ cb11, const int* __restrict__ i11,
    const float* __restrict__ cb12, const int* __restrict__ i12,
    const float* __restrict__ cb20, const int* __restrict__ i20,
    const float* __restrict__ cb21, const int* __restrict__ i21,
    const float* __restrict__ cb22, const int* __restrict__ i22,
    float* __restrict__ out)
{
    const int nwg  = gridDim.x;
    const int perx = nwg >> 3;
    const int blk  = blockIdx.x;
    const int xcd  = blk & 7;
    const int hh   = xcd >> 2;
    const int wh   = (xcd & 3) * perx + (blk >> 3);

    const int t   = (int)threadIdx.x;
    const int sub = (t >> 4) & 1;
    const int li  = t & 15;
    const int ii  = wh * 16 + ((t >> 5) << 1) + sub;
    const int f   = ii >> 12;
    const int bb  = ii & (BB - 1);
    const int d0  = (hh << 6) + (li << 2);

    const int xg = x[bb * FF + f] + f * FIELD_DIM;
    const float* ap = arch_prob + f * 9;
    const int k4 = (hh << 1) + (li >> 3);

    int r00 = i00[xg];
    int r10 = i10[xg];
    int r11 = i11[(size_t)xg * 2 + hh];
    int r12 = i12[(size_t)xg * 4 + k4];
    int r20 = i20[xg];
    int r21 = i21[(size_t)xg * 2 + hh];
    int r22 = i22[(size_t)xg * 4 + k4];

    float4 acc = make_float4(0.f, 0.f, 0.f, 0.f);

#define GATHER_FMA(cb, r, col)                                                \
    do {                                                                      \
        float4 v = *reinterpret_cast<const float4*>((cb) + (size_t)(r) * DD + d0); \
        float s = ap[col];                                                    \
        acc.x += s * v.x; acc.y += s * v.y;                                   \
        acc.z += s * v.z; acc.w += s * v.w;                                   \
    } while (0)

    GATHER_FMA(cb00, r00, 0);
    GATHER_FMA(cb10, r10, 3);
    GATHER_FMA(cb11, r11, 4);
    GATHER_FMA(cb12, r12, 5);
    GATHER_FMA(cb20, r20, 6);
    GATHER_FMA(cb21, r21, 7);
    GATHER_FMA(cb22, r22, 8);
#undef GATHER_FMA

    float* dst = out + ((size_t)bb * FF + f) * DD + d0;
    __builtin_nontemporal_store(acc.x, dst + 0);
    __builtin_nontemporal_store(acc.y, dst + 1);
    __builtin_nontemporal_store(acc.z, dst + 2);
    __builtin_nontemporal_store(acc.w, dst + 3);
}

extern "C" void kernel_launch(void* const* d_in, const int* in_sizes, int n_in,
                              void* d_out, int out_size, void* d_ws, size_t ws_size,
                              hipStream_t stream) {
    const int*   x  = (const int*)d_in[0];
    const float* ap = (const float*)d_in[1];
    const float* cb00 = (const float*)d_in[2];
    const int*   i00  = (const int*)d_in[3];
    const float* cb10 = (const float*)d_in[4];
    const int*   i10  = (const int*)d_in[5];
    const float* cb11 = (const float*)d_in[6];
    const int*   i11  = (const int*)d_in[7];
    const float* cb12 = (const float*)d_in[8];
    const int*   i12  = (const int*)d_in[9];
    const float* cb20 = (const float*)d_in[10];
    const int*   i20  = (const int*)d_in[11];
    const float* cb21 = (const float*)d_in[12];
    const int*   i21  = (const int*)d_in[13];
    const float* cb22 = (const float*)d_in[14];
    const int*   i22  = (const int*)d_in[15];
    float* out = (float*)d_out;

    if (ws_size >= ROWS_WS_BYTES) {
        uint4* rows_ws = (uint4*)d_ws;
        pass1_resolve<<<NITEMS / 256, 256, 0, stream>>>(
            x, i00, i10, i11, i12, i20, i21, i22, rows_ws);
        pass2_gather<<<(NITEMS / 32) * 4, 256, 0, stream>>>(
            ap, cb00, cb10, cb11, cb12, cb20, cb21, cb22, rows_ws, out);
    } else {
        const long long total_threads = (long long)BB * FF * 32;
        const int blocks = (int)((total_threads + 255) / 256);
        mixq_embed<<<blocks, 256, 0, stream>>>(
            x, ap, cb00, i00, cb10, i10, cb11, i11, cb12, i12,
            cb20, i20, cb21, i21, cb22, i22, out);
    }
}

// Round 7
// 78.557 us; speedup vs baseline: 1.7048x; 1.0204x over previous
//
#include <hip/hip_runtime.h>

#define BB 4096
#define FF 39
#define DD 128
#define FIELD_DIM 10000
#define NITEMS (BB * FF)          // 159744
#define ROWS_WS_BYTES ((size_t)4 * NITEMS * 16)   // 10,223,616

typedef unsigned uint4v __attribute__((ext_vector_type(4)));

// ============================ Pass 1 =====================================
// One thread per item, f-major + XCD-chunked (idx tables L2-resident).
// Per d-quarter q: 16 B record {r00,r10 | r20,r11[q>>1] | r21[q>>1],r12[q] | r22[q]}.
__global__ __launch_bounds__(256) void pass1_resolve(
    const int* __restrict__ x,
    const int* __restrict__ i00, const int* __restrict__ i10,
    const int* __restrict__ i11, const int* __restrict__ i12,
    const int* __restrict__ i20, const int* __restrict__ i21,
    const int* __restrict__ i22,
    uint4* __restrict__ rows_ws)
{
    const int nwg = gridDim.x;              // 624, %8==0
    const int cpx = nwg >> 3;
    const int blk = blockIdx.x;
    const int wg  = (blk & 7) * cpx + (blk >> 3);
    const int i   = wg * 256 + (int)threadIdx.x;   // f-major item id
    const int f   = i >> 12;
    const int b   = i & (BB - 1);
    const int xg  = x[b * FF + f] + f * FIELD_DIM;

    const unsigned r00 = (unsigned)i00[xg];
    const unsigned r10 = (unsigned)i10[xg];
    const unsigned r20 = (unsigned)i20[xg];
    const int2 v11 = *reinterpret_cast<const int2*>(i11 + (size_t)xg * 2);
    const int2 v21 = *reinterpret_cast<const int2*>(i21 + (size_t)xg * 2);
    const int4 v12 = *reinterpret_cast<const int4*>(i12 + (size_t)xg * 4);
    const int4 v22 = *reinterpret_cast<const int4*>(i22 + (size_t)xg * 4);

    const unsigned w0 = r00 | (r10 << 16);
    const unsigned r11k[2] = { (unsigned)v11.x, (unsigned)v11.y };
    const unsigned r21k[2] = { (unsigned)v21.x, (unsigned)v21.y };
    const unsigned r12k[4] = { (unsigned)v12.x, (unsigned)v12.y,
                               (unsigned)v12.z, (unsigned)v12.w };
    const unsigned r22k[4] = { (unsigned)v22.x, (unsigned)v22.y,
                               (unsigned)v22.z, (unsigned)v22.w };

#pragma unroll
    for (int q = 0; q < 4; ++q) {
        uint4 rec;
        rec.x = w0;
        rec.y = r20 | (r11k[q >> 1] << 16);
        rec.z = r21k[q >> 1] | (r12k[q] << 16);
        rec.w = r22k[q];
        rows_ws[(size_t)q * NITEMS + i] = rec;
    }
}

// ============================ Pass 2 =====================================
// d-QUARTER split (XCD pair {2q,2q+1} owns d in [q*32,q*32+32), 128 B lines,
// no straddle). TWO items per thread -> 14 independent gathers in flight.
// Records loaded non-temporally so the 2.5 MB/XCD record stream doesn't
// evict codebook lines from L2. Block: 256 thr = 64 items x 8 lanes.
__global__ __launch_bounds__(256) void pass2_gather(
    const float* __restrict__ arch_prob,
    const float* __restrict__ cb00, const float* __restrict__ cb10,
    const float* __restrict__ cb11, const float* __restrict__ cb12,
    const float* __restrict__ cb20, const float* __restrict__ cb21,
    const float* __restrict__ cb22,
    const uint4* __restrict__ rows_ws,
    float* __restrict__ out)
{
    const int blk = blockIdx.x;               // 9984 blocks
    const int xcd = blk & 7;
    const int q   = xcd >> 1;                 // d-quarter of this XCD pair
    const int ph  = xcd & 1;                  // item half within the pair
    const int seq = blk >> 3;                 // [0, 1248)

    const int t    = (int)threadIdx.x;
    const int li   = t & 7;                   // lane within item
    const int d0   = q * 32 + li * 4;
    const int base = ph * (NITEMS / 2) + seq * 64;
    const int i0   = base + (t >> 3);         // first item
    const int i1   = i0 + 32;                 // second item

    const uint4v rw0 = __builtin_nontemporal_load(
        reinterpret_cast<const uint4v*>(rows_ws + (size_t)q * NITEMS + i0));
    const uint4v rw1 = __builtin_nontemporal_load(
        reinterpret_cast<const uint4v*>(rows_ws + (size_t)q * NITEMS + i1));

    const int f0 = i0 >> 12, b0 = i0 & (BB - 1);
    const int f1 = i1 >> 12, b1 = i1 & (BB - 1);
    const float* ap0 = arch_prob + f0 * 9;
    const float* ap1 = arch_prob + f1 * 9;

    float4 acc0 = make_float4(0.f, 0.f, 0.f, 0.f);
    float4 acc1 = make_float4(0.f, 0.f, 0.f, 0.f);

#define GF(cb, rw, idx, shift, ap, col, acc)                                  \
    do {                                                                      \
        int r = (int)((rw[idx] >> (shift)) & 0xffffu);                        \
        float4 v = *reinterpret_cast<const float4*>((cb) + (size_t)r * DD + d0); \
        float s = (ap)[col];                                                  \
        acc.x += s * v.x; acc.y += s * v.y;                                   \
        acc.z += s * v.z; acc.w += s * v.w;                                   \
    } while (0)

    // Reference pair order per item -> identical fp32 accumulation order.
    GF(cb00, rw0, 0,  0, ap0, 0, acc0);  GF(cb00, rw1, 0,  0, ap1, 0, acc1);
    GF(cb10, rw0, 0, 16, ap0, 3, acc0);  GF(cb10, rw1, 0, 16, ap1, 3, acc1);
    GF(cb11, rw0, 1, 16, ap0, 4, acc0);  GF(cb11, rw1, 1, 16, ap1, 4, acc1);
    GF(cb12, rw0, 2, 16, ap0, 5, acc0);  GF(cb12, rw1, 2, 16, ap1, 5, acc1);
    GF(cb20, rw0, 1,  0, ap0, 6, acc0);  GF(cb20, rw1, 1,  0, ap1, 6, acc1);
    GF(cb21, rw0, 2,  0, ap0, 7, acc0);  GF(cb21, rw1, 2,  0, ap1, 7, acc1);
    GF(cb22, rw0, 3,  0, ap0, 8, acc0);  GF(cb22, rw1, 3,  0, ap1, 8, acc1);
#undef GF

    float* dst0 = out + ((size_t)b0 * FF + f0) * DD + d0;
    float* dst1 = out + ((size_t)b1 * FF + f1) * DD + d0;
    __builtin_nontemporal_store(acc0.x, dst0 + 0);
    __builtin_nontemporal_store(acc0.y, dst0 + 1);
    __builtin_nontemporal_store(acc0.z, dst0 + 2);
    __builtin_nontemporal_store(acc0.w, dst0 + 3);
    __builtin_nontemporal_store(acc1.x, dst1 + 0);
    __builtin_nontemporal_store(acc1.y, dst1 + 1);
    __builtin_nontemporal_store(acc1.z, dst1 + 2);
    __builtin_nontemporal_store(acc1.w, dst1 + 3);
}

// ===================== Fallback (R3 single-pass) =========================
__global__ __launch_bounds__(256) void mixq_embed(
    const int* __restrict__ x,
    const float* __restrict__ arch_prob,
    const float* __restrict__ cb00, const int* __restrict__ i00,
    const float* __restrict__ cb10, const int* __restrict__ i10,
    const float* __restrict__ cb11, const int* __restrict__ i11,
    const float* __restrict__ cb12, const int* __restrict__ i12,
    const float* __restrict__ cb20, const int* __restrict__ i20,
    const float* __restrict__ cb21, const int* __restrict__ i21,
    const float* __restrict__ cb22, const int* __restrict__ i22,
    float* __restrict__ out)
{
    const int nwg  = gridDim.x;
    const int perx = nwg >> 3;
    const int blk  = blockIdx.x;
    const int xcd  = blk & 7;
    const int hh   = xcd >> 2;
    const int wh   = (xcd & 3) * perx + (blk >> 3);

    const int t   = (int)threadIdx.x;
    const int sub = (t >> 4) & 1;
    const int li  = t & 15;
    const int ii  = wh * 16 + ((t >> 5) << 1) + sub;
    const int f   = ii >> 12;
    const int bb  = ii & (BB - 1);
    const int d0  = (hh << 6) + (li << 2);

    const int xg = x[bb * FF + f] + f * FIELD_DIM;
    const float* ap = arch_prob + f * 9;
    const int k4 = (hh << 1) + (li >> 3);

    int r00 = i00[xg];
    int r10 = i10[xg];
    int r11 = i11[(size_t)xg * 2 + hh];
    int r12 = i12[(size_t)xg * 4 + k4];
    int r20 = i20[xg];
    int r21 = i21[(size_t)xg * 2 + hh];
    int r22 = i22[(size_t)xg * 4 + k4];

    float4 acc = make_float4(0.f, 0.f, 0.f, 0.f);

#define GATHER_FMA(cb, r, col)                                                \
    do {                                                                      \
        float4 v = *reinterpret_cast<const float4*>((cb) + (size_t)(r) * DD + d0); \
        float s = ap[col];                                                    \
        acc.x += s * v.x; acc.y += s * v.y;                                   \
        acc.z += s * v.z; acc.w += s * v.w;                                   \
    } while (0)

    GATHER_FMA(cb00, r00, 0);
    GATHER_FMA(cb10, r10, 3);
    GATHER_FMA(cb11, r11, 4);
    GATHER_FMA(cb12, r12, 5);
    GATHER_FMA(cb20, r20, 6);
    GATHER_FMA(cb21, r21, 7);
    GATHER_FMA(cb22, r22, 8);
#undef GATHER_FMA

    float* dst = out + ((size_t)bb * FF + f) * DD + d0;
    __builtin_nontemporal_store(acc.x, dst + 0);
    __builtin_nontemporal_store(acc.y, dst + 1);
    __builtin_nontemporal_store(acc.z, dst + 2);
    __builtin_nontemporal_store(acc.w, dst + 3);
}

extern "C" void kernel_launch(void* const* d_in, const int* in_sizes, int n_in,
                              void* d_out, int out_size, void* d_ws, size_t ws_size,
                              hipStream_t stream) {
    const int*   x  = (const int*)d_in[0];
    const float* ap = (const float*)d_in[1];
    const float* cb00 = (const float*)d_in[2];
    const int*   i00  = (const int*)d_in[3];
    const float* cb10 = (const float*)d_in[4];
    const int*   i10  = (const int*)d_in[5];
    const float* cb11 = (const float*)d_in[6];
    const int*   i11  = (const int*)d_in[7];
    const float* cb12 = (const float*)d_in[8];
    const int*   i12  = (const int*)d_in[9];
    const float* cb20 = (const float*)d_in[10];
    const int*   i20  = (const int*)d_in[11];
    const float* cb21 = (const float*)d_in[12];
    const int*   i21  = (const int*)d_in[13];
    const float* cb22 = (const float*)d_in[14];
    const int*   i22  = (const int*)d_in[15];
    float* out = (float*)d_out;

    if (ws_size >= ROWS_WS_BYTES) {
        uint4* rows_ws = (uint4*)d_ws;
        pass1_resolve<<<NITEMS / 256, 256, 0, stream>>>(
            x, i00, i10, i11, i12, i20, i21, i22, rows_ws);
        pass2_gather<<<(NITEMS / 64) * 4, 256, 0, stream>>>(
            ap, cb00, cb10, cb11, cb12, cb20, cb21, cb22, rows_ws, out);
    } else {
        const long long total_threads = (long long)BB * FF * 32;
        const int blocks = (int)((total_threads + 255) / 256);
        mixq_embed<<<blocks, 256, 0, stream>>>(
            x, ap, cb00, i00, cb10, i10, cb11, i11, cb12, i12,
            cb20, i20, cb21, i21, cb22, i22, out);
    }
}

// Round 8
// 77.051 us; speedup vs baseline: 1.7381x; 1.0195x over previous
//
#include <hip/hip_runtime.h>

#define BB 4096
#define FF 39
#define DD 128
#define FIELD_DIM 10000
#define NITEMS (BB * FF)          // 159744
#define ROWS_WS_BYTES ((size_t)4 * NITEMS * 16)   // 10,223,616

typedef unsigned uint4v __attribute__((ext_vector_type(4)));

// ============================ Pass 1 =====================================
// One thread per item, f-major + XCD-chunked (idx tables L2-resident).
// Per d-quarter q: 16 B record {r00,r10 | r20,r11[q>>1] | r21[q>>1],r12[q] | r22[q]}.
__global__ __launch_bounds__(256) void pass1_resolve(
    const int* __restrict__ x,
    const int* __restrict__ i00, const int* __restrict__ i10,
    const int* __restrict__ i11, const int* __restrict__ i12,
    const int* __restrict__ i20, const int* __restrict__ i21,
    const int* __restrict__ i22,
    uint4* __restrict__ rows_ws)
{
    const int nwg = gridDim.x;              // 624, %8==0
    const int cpx = nwg >> 3;
    const int blk = blockIdx.x;
    const int wg  = (blk & 7) * cpx + (blk >> 3);
    const int i   = wg * 256 + (int)threadIdx.x;   // f-major item id
    const int f   = i >> 12;
    const int b   = i & (BB - 1);
    const int xg  = x[b * FF + f] + f * FIELD_DIM;

    const unsigned r00 = (unsigned)i00[xg];
    const unsigned r10 = (unsigned)i10[xg];
    const unsigned r20 = (unsigned)i20[xg];
    const int2 v11 = *reinterpret_cast<const int2*>(i11 + (size_t)xg * 2);
    const int2 v21 = *reinterpret_cast<const int2*>(i21 + (size_t)xg * 2);
    const int4 v12 = *reinterpret_cast<const int4*>(i12 + (size_t)xg * 4);
    const int4 v22 = *reinterpret_cast<const int4*>(i22 + (size_t)xg * 4);

    const unsigned w0 = r00 | (r10 << 16);
    const unsigned r11k[2] = { (unsigned)v11.x, (unsigned)v11.y };
    const unsigned r21k[2] = { (unsigned)v21.x, (unsigned)v21.y };
    const unsigned r12k[4] = { (unsigned)v12.x, (unsigned)v12.y,
                               (unsigned)v12.z, (unsigned)v12.w };
    const unsigned r22k[4] = { (unsigned)v22.x, (unsigned)v22.y,
                               (unsigned)v22.z, (unsigned)v22.w };

#pragma unroll
    for (int q = 0; q < 4; ++q) {
        uint4 rec;
        rec.x = w0;
        rec.y = r20 | (r11k[q >> 1] << 16);
        rec.z = r21k[q >> 1] | (r12k[q] << 16);
        rec.w = r22k[q];
        rows_ws[(size_t)q * NITEMS + i] = rec;
    }
}

// ============================ Pass 2 =====================================
// d-QUARTER split (XCD pair {2q,2q+1} owns d in [q*32,q*32+32)) with
// BOOK-PHASED gathering: book loop OUTER, __syncthreads() between books,
// 4 items per thread. All concurrently-running waves on an XCD gather from
// ~one book at a time, so the instantaneous L2 pool is one book's quarter
// slice (1.3-2.5 MB << 4 MB L2) instead of all seven (13.9 MB).
// Block: 256 thr = 32 item-slots x 8 lanes; 4 items per slot = 128 items.
__global__ __launch_bounds__(256) void pass2_gather(
    const float* __restrict__ arch_prob,
    const float* __restrict__ cb00, const float* __restrict__ cb10,
    const float* __restrict__ cb11, const float* __restrict__ cb12,
    const float* __restrict__ cb20, const float* __restrict__ cb21,
    const float* __restrict__ cb22,
    const uint4* __restrict__ rows_ws,
    float* __restrict__ out)
{
    const int blk = blockIdx.x;               // 4992 blocks
    const int xcd = blk & 7;
    const int q   = xcd >> 1;                 // d-quarter of this XCD pair
    const int ph  = xcd & 1;                  // item half within the pair
    const int seq = blk >> 3;                 // [0, 624)

    const int t    = (int)threadIdx.x;
    const int li   = t & 7;                   // lane within item (8 x float4)
    const int slot = t >> 3;                  // 32 slots
    const int d0   = q * 32 + li * 4;
    const int base = ph * (NITEMS / 2) + seq * 128 + slot;

    int  ii[4];
    int  ff[4];
    int  bb[4];
    uint4v rw[4];
#pragma unroll
    for (int j = 0; j < 4; ++j) {
        ii[j] = base + 32 * j;
        ff[j] = ii[j] >> 12;
        bb[j] = ii[j] & (BB - 1);
        rw[j] = __builtin_nontemporal_load(
            reinterpret_cast<const uint4v*>(rows_ws + (size_t)q * NITEMS + ii[j]));
    }

    float4 acc[4];
#pragma unroll
    for (int j = 0; j < 4; ++j) acc[j] = make_float4(0.f, 0.f, 0.f, 0.f);

    // One book per phase, reference order -> per-element accumulation order
    // identical to the reference. __syncthreads keeps the block (and, by
    // launch alignment, the XCD) on the same book at the same time.
#define BOOK_PHASE(cb, widx, shift, col)                                      \
    do {                                                                      \
        _Pragma("unroll")                                                     \
        for (int j = 0; j < 4; ++j) {                                         \
            int r = (int)((rw[j][widx] >> (shift)) & 0xffffu);                \
            float4 v = *reinterpret_cast<const float4*>(                      \
                (cb) + (size_t)r * DD + d0);                                  \
            float s = arch_prob[ff[j] * 9 + (col)];                           \
            acc[j].x += s * v.x; acc[j].y += s * v.y;                         \
            acc[j].z += s * v.z; acc[j].w += s * v.w;                         \
        }                                                                     \
        __syncthreads();                                                      \
    } while (0)

    BOOK_PHASE(cb00, 0,  0, 0);
    BOOK_PHASE(cb10, 0, 16, 3);
    BOOK_PHASE(cb11, 1, 16, 4);
    BOOK_PHASE(cb12, 2, 16, 5);
    BOOK_PHASE(cb20, 1,  0, 6);
    BOOK_PHASE(cb21, 2,  0, 7);
    BOOK_PHASE(cb22, 3,  0, 8);
#undef BOOK_PHASE

#pragma unroll
    for (int j = 0; j < 4; ++j) {
        float* dst = out + ((size_t)bb[j] * FF + ff[j]) * DD + d0;
        __builtin_nontemporal_store(acc[j].x, dst + 0);
        __builtin_nontemporal_store(acc[j].y, dst + 1);
        __builtin_nontemporal_store(acc[j].z, dst + 2);
        __builtin_nontemporal_store(acc[j].w, dst + 3);
    }
}

// ===================== Fallback (R3 single-pass) =========================
__global__ __launch_bounds__(256) void mixq_embed(
    const int* __restrict__ x,
    const float* __restrict__ arch_prob,
    const float* __restrict__ cb00, const int* __restrict__ i00,
    const float* __restrict__ cb10, const int* __restrict__ i10,
    const float* __restrict__ cb11, const int* __restrict__ i11,
    const float* __restrict__ cb12, const int* __restrict__ i12,
    const float* __restrict__ cb20, const int* __restrict__ i20,
    const float* __restrict__ cb21, const int* __restrict__ i21,
    const float* __restrict__ cb22, const int* __restrict__ i22,
    float* __restrict__ out)
{
    const int nwg  = gridDim.x;
    const int perx = nwg >> 3;
    const int blk  = blockIdx.x;
    const int xcd  = blk & 7;
    const int hh   = xcd >> 2;
    const int wh   = (xcd & 3) * perx + (blk >> 3);

    const int t   = (int)threadIdx.x;
    const int sub = (t >> 4) & 1;
    const int li  = t & 15;
    const int ii  = wh * 16 + ((t >> 5) << 1) + sub;
    const int f   = ii >> 12;
    const int bb  = ii & (BB - 1);
    const int d0  = (hh << 6) + (li << 2);

    const int xg = x[bb * FF + f] + f * FIELD_DIM;
    const float* ap = arch_prob + f * 9;
    const int k4 = (hh << 1) + (li >> 3);

    int r00 = i00[xg];
    int r10 = i10[xg];
    int r11 = i11[(size_t)xg * 2 + hh];
    int r12 = i12[(size_t)xg * 4 + k4];
    int r20 = i20[xg];
    int r21 = i21[(size_t)xg * 2 + hh];
    int r22 = i22[(size_t)xg * 4 + k4];

    float4 acc = make_float4(0.f, 0.f, 0.f, 0.f);

#define GATHER_FMA(cb, r, col)                                                \
    do {                                                                      \
        float4 v = *reinterpret_cast<const float4*>((cb) + (size_t)(r) * DD + d0); \
        float s = ap[col];                                                    \
        acc.x += s * v.x; acc.y += s * v.y;                                   \
        acc.z += s * v.z; acc.w += s * v.w;                                   \
    } while (0)

    GATHER_FMA(cb00, r00, 0);
    GATHER_FMA(cb10, r10, 3);
    GATHER_FMA(cb11, r11, 4);
    GATHER_FMA(cb12, r12, 5);
    GATHER_FMA(cb20, r20, 6);
    GATHER_FMA(cb21, r21, 7);
    GATHER_FMA(cb22, r22, 8);
#undef GATHER_FMA

    float* dst = out + ((size_t)bb * FF + f) * DD + d0;
    __builtin_nontemporal_store(acc.x, dst + 0);
    __builtin_nontemporal_store(acc.y, dst + 1);
    __builtin_nontemporal_store(acc.z, dst + 2);
    __builtin_nontemporal_store(acc.w, dst + 3);
}

extern "C" void kernel_launch(void* const* d_in, const int* in_sizes, int n_in,
                              void* d_out, int out_size, void* d_ws, size_t ws_size,
                              hipStream_t stream) {
    const int*   x  = (const int*)d_in[0];
    const float* ap = (const float*)d_in[1];
    const float* cb00 = (const float*)d_in[2];
    const int*   i00  = (const int*)d_in[3];
    const float* cb10 = (const float*)d_in[4];
    const int*   i10  = (const int*)d_in[5];
    const float* cb11 = (const float*)d_in[6];
    const int*   i11  = (const int*)d_in[7];
    const float* cb12 = (const float*)d_in[8];
    const int*   i12  = (const int*)d_in[9];
    const float* cb20 = (const float*)d_in[10];
    const int*   i20  = (const int*)d_in[11];
    const float* cb21 = (const float*)d_in[12];
    const int*   i21  = (const int*)d_in[13];
    const float* cb22 = (const float*)d_in[14];
    const int*   i22  = (const int*)d_in[15];
    float* out = (float*)d_out;

    if (ws_size >= ROWS_WS_BYTES) {
        uint4* rows_ws = (uint4*)d_ws;
        pass1_resolve<<<NITEMS / 256, 256, 0, stream>>>(
            x, i00, i10, i11, i12, i20, i21, i22, rows_ws);
        pass2_gather<<<(NITEMS / 128) * 4, 256, 0, stream>>>(
            ap, cb00, cb10, cb11, cb12, cb20, cb21, cb22, rows_ws, out);
    } else {
        const long long total_threads = (long long)BB * FF * 32;
        const int blocks = (int)((total_threads + 255) / 256);
        mixq_embed<<<blocks, 256, 0, stream>>>(
            x, ap, cb00, i00, cb10, i10, cb11, i11, cb12, i12,
            cb20, i20, cb21, i21, cb22, i22, out);
    }
}